// Round 8
// baseline (713.846 us; speedup 1.0000x reference)
//
#include <hip/hip_runtime.h>
#include <hip/hip_bf16.h>
#include <stdint.h>

// Problem constants
//  L=4, MM=2, C=128, H=64, OUTC=128, EDGE_CH=128, X_EDGE=384, C3=384
//  NRED=19, NFULL=25, E=10000
//  Effective w_m0 rows 512..1087 (576 outs, padded to 640)

__constant__ int c_MASKP[19] = {0,2,6,12,20, 3,7,13,21, 1,5,11,19, 8,14,22, 4,10,18};
__constant__ int c_GATEP[19] = {-1,0,1,2,3, 0,1,2,3, 0,1,2,3, 1,2,3, 1,2,3};
__constant__ int c_LFULL[25] = {0,1,1,1,2,2,2,2,2,3,3,3,3,3,3,3,4,4,4,4,4,4,4,4,4};

__device__ __forceinline__ float sigm_(float x) { return 1.f / (1.f + __expf(-x)); }

typedef __attribute__((ext_vector_type(8))) __bf16 bf16x8;
typedef __attribute__((ext_vector_type(4))) float floatx4;

__device__ __forceinline__ void async16(const void* g, void* l) {
    __builtin_amdgcn_global_load_lds(
        (__attribute__((address_space(1))) void*)(g),
        (__attribute__((address_space(3))) void*)(l), 16, 0, 0);
}

// ---------------------------------------------------------------------------
// K0': split proj_w (5,128,64) fp32 -> pwb (5,128,192) bf16 as [hi | lo | hi]
__global__ void k_split_pw(const float* __restrict__ pw, __hip_bfloat16* __restrict__ pwb) {
    int d = blockIdx.x * 256 + threadIdx.x;
    if (d >= 40960) return;                 // 5*128*64
    int ll = d >> 13, rem = d & 8191;
    int o = rem >> 6, i = rem & 63;
    float v = pw[d];
    __hip_bfloat16 hi = __float2bfloat16(v);
    __hip_bfloat16 lo = __float2bfloat16(v - __bfloat162float(hi));
    long ob = (long)(ll * 128 + o) * 192;
    pwb[ob + i]       = hi;
    pwb[ob + 64 + i]  = lo;
    pwb[ob + 128 + i] = hi;
}

// ---------------------------------------------------------------------------
// Kc: fp32 weight [rows][K] -> bf16 [rowsPad][K], pad rows zero
__global__ void k_cvt_w(const float* __restrict__ W, __hip_bfloat16* __restrict__ out,
                        int rows, int rowsPad, int K) {
    long i = (long)blockIdx.x * 256 + threadIdx.x;
    if (i >= (long)rowsPad * K) return;
    int r = (int)(i / K);
    out[i] = __float2bfloat16(r < rows ? W[i] : 0.f);
}

// ---------------------------------------------------------------------------
// Kc': fp32 weight [rows][K] -> split bf16 [rows][3K] = [hi | lo | hi]
__global__ void k_cvt_w_split(const float* __restrict__ W, __hip_bfloat16* __restrict__ out,
                              int rows, int K) {
    long i = (long)blockIdx.x * 256 + threadIdx.x;
    if (i >= (long)rows * K) return;
    int r = (int)(i / K), k = (int)(i - (long)r * K);
    float v = W[i];
    __hip_bfloat16 hi = __float2bfloat16(v);
    __hip_bfloat16 lo = __float2bfloat16(v - __bfloat162float(hi));
    long ob = (long)r * 3 * K;
    out[ob + k]         = hi;
    out[ob + K + k]     = lo;
    out[ob + 2 * K + k] = hi;
}

// ---------------------------------------------------------------------------
// K1a: gather x_edge = [ed | se[an[src]] | te[an[tgt]]] -> split bf16 [CE][1152]
__global__ __launch_bounds__(256) void k_build_xedge(
    const float* __restrict__ ed, const float* __restrict__ se, const float* __restrict__ te,
    const int* __restrict__ an, const int* __restrict__ eidx,
    __hip_bfloat16* __restrict__ xeb, int e0, int ec, int E)
{
    long i = (long)blockIdx.x * 256 + threadIdx.x;
    if (i >= (long)ec * 384) return;
    int le = (int)(i / 384), c = (int)(i - (long)le * 384);
    int e = e0 + le;
    float v;
    if (c < 128)       v = ed[(long)e * 128 + c];
    else if (c < 256)  { int s = eidx[e];     v = se[an[s] * 128 + (c - 128)]; }
    else               { int t = eidx[E + e]; v = te[an[t] * 128 + (c - 256)]; }
    __hip_bfloat16 hi = __float2bfloat16(v);
    __hip_bfloat16 lo = __float2bfloat16(v - __bfloat162float(hi));
    long ob = (long)le * 1152;
    xeb[ob + c]       = hi;
    xeb[ob + 384 + c] = hi;
    xeb[ob + 768 + c] = lo;
}

// ---------------------------------------------------------------------------
// K1b: per-row LayerNorm + SiLU on fp32 [ec][128].
__global__ __launch_bounds__(256) void k_ln_silu(
    const float* __restrict__ H, const float* __restrict__ g, const float* __restrict__ bb,
    __hip_bfloat16* __restrict__ out, int ec, int split)
{
    int row = blockIdx.x * 4 + (threadIdx.x >> 6);
    if (row >= ec) return;
    int lane = threadIdx.x & 63;
    const float* hr = H + (long)row * 128;
    float v0 = hr[lane], v1 = hr[lane + 64];
    float s = v0 + v1, s2 = v0 * v0 + v1 * v1;
    #pragma unroll
    for (int o = 32; o >= 1; o >>= 1) {
        s  += __shfl_xor(s, o, 64);
        s2 += __shfl_xor(s2, o, 64);
    }
    float mu = s * (1.f / 128.f);
    float rs = rsqrtf(s2 * (1.f / 128.f) - mu * mu + 1e-5f);
    float a0 = (v0 - mu) * rs * g[lane]      + bb[lane];
    float a1 = (v1 - mu) * rs * g[lane + 64] + bb[lane + 64];
    a0 = a0 * sigm_(a0);
    a1 = a1 * sigm_(a1);
    if (split) {
        long ob = (long)row * 384;
        __hip_bfloat16 h0 = __float2bfloat16(a0);
        __hip_bfloat16 l0 = __float2bfloat16(a0 - __bfloat162float(h0));
        __hip_bfloat16 h1 = __float2bfloat16(a1);
        __hip_bfloat16 l1 = __float2bfloat16(a1 - __bfloat162float(h1));
        out[ob + lane]            = h0;
        out[ob + 128 + lane]      = h0;
        out[ob + 256 + lane]      = l0;
        out[ob + lane + 64]       = h1;
        out[ob + 128 + lane + 64] = h1;
        out[ob + 256 + lane + 64] = l1;
    } else {
        long ob = (long)row * 128;
        out[ob + lane]      = __float2bfloat16(a0);
        out[ob + lane + 64] = __float2bfloat16(a1);
    }
}

// ---------------------------------------------------------------------------
// Shared MFMA GEMM body (m97 structure): Out[r][o] = sum_k A[r][k]*B[o][k]
// ntStore!=0 -> nontemporal output stores (write-once data; protect L2)
__device__ __forceinline__ void gemm_body(
    __hip_bfloat16* As, __hip_bfloat16* Bs,
    const __hip_bfloat16* A, const __hip_bfloat16* B,
    const float* bias, float* Out, int ldo,
    int realM, int realN, int K, int r0, int n0, int tid, int ntStore)
{
    int l = tid & 63, w = tid >> 6;
    int wm = w & 1, wn = w >> 1;

    floatx4 acc[4][4] = {};

    int srow = w * 16 + (l >> 2);
    int scol = (l & 3) * 8;
    const __hip_bfloat16* Ag = A + (long)(r0 + srow) * K + scol;
    const __hip_bfloat16* Bg = B + (long)(n0 + srow) * K + scol;
    __hip_bfloat16* AsW = As + (w * 16) * 32;
    __hip_bfloat16* BsW = Bs + (w * 16) * 32;

    int lrow = l & 15, lk = (l >> 4) * 8;

    for (int kk = 0; kk < K; kk += 32) {
        async16(Ag + kk, AsW);
        async16(Ag + (long)64 * K + kk, AsW + 64 * 32);
        async16(Bg + kk, BsW);
        async16(Bg + (long)64 * K + kk, BsW + 64 * 32);
        __syncthreads();
        bf16x8 af[4], bf[4];
        #pragma unroll
        for (int mi = 0; mi < 4; ++mi)
            af[mi] = *(const bf16x8*)&As[(wm * 64 + mi * 16 + lrow) * 32 + lk];
        #pragma unroll
        for (int ni = 0; ni < 4; ++ni)
            bf[ni] = *(const bf16x8*)&Bs[(wn * 64 + ni * 16 + lrow) * 32 + lk];
        #pragma unroll
        for (int mi = 0; mi < 4; ++mi)
            #pragma unroll
            for (int ni = 0; ni < 4; ++ni)
                acc[mi][ni] = __builtin_amdgcn_mfma_f32_16x16x32_bf16(
                    af[mi], bf[ni], acc[mi][ni], 0, 0, 0);
        __syncthreads();
    }

    int lq = l >> 4;
    #pragma unroll
    for (int ni = 0; ni < 4; ++ni) {
        int col = n0 + wn * 64 + ni * 16 + lrow;
        if (col >= realN) continue;
        float bv = bias ? bias[col] : 0.f;
        #pragma unroll
        for (int mi = 0; mi < 4; ++mi) {
            int rbase = r0 + wm * 64 + mi * 16 + lq * 4;
            floatx4 v = acc[mi][ni];
            #pragma unroll
            for (int r = 0; r < 4; ++r) {
                int row = rbase + r;
                if (row < realM) {
                    float vv = v[r] + bv;
                    if (ntStore) __builtin_nontemporal_store(vv, &Out[(long)row * ldo + col]);
                    else         Out[(long)row * ldo + col] = vv;
                }
            }
        }
    }
}

// ---------------------------------------------------------------------------
// K2: standalone MFMA GEMM (grid (Mpad/128, Npad/128))
__global__ __launch_bounds__(256) void k_mfma_gemm(
    const __hip_bfloat16* __restrict__ A,
    const __hip_bfloat16* __restrict__ B,
    const float* __restrict__ bias,
    float* __restrict__ Out, int ldo,
    int realM, int realN, int K)
{
    __shared__ __align__(16) __hip_bfloat16 As[128 * 32];
    __shared__ __align__(16) __hip_bfloat16 Bs[128 * 32];
    gemm_body(As, Bs, A, B, bias, Out, ldo, realM, realN, K,
              blockIdx.x * 128, blockIdx.y * 128, threadIdx.x, 0);
}

// ---------------------------------------------------------------------------
// K2' v2: merged y-GEMMs with A-panel-major tile order + bijective XCD remap.
// Physical blockIdx round-robins XCDs; remap (m204) chunks logical tile IDs
// per XCD so the 5/4/3 tiles sharing one A row-panel run on the SAME XCD
// and hit its L2 instead of re-fetching from HBM. Outputs stored nontemporal
// (write-once, read later; keeps A-panels resident).
__global__ __launch_bounds__(256) void k_mfma_gemm3(
    const __hip_bfloat16* __restrict__ A0, const __hip_bfloat16* __restrict__ B0,
    const float* __restrict__ bias0, float* __restrict__ O0,
    const __hip_bfloat16* __restrict__ A1, const __hip_bfloat16* __restrict__ B1,
    float* __restrict__ O1,
    const __hip_bfloat16* __restrict__ A2, const __hip_bfloat16* __restrict__ B2,
    float* __restrict__ O2,
    int mt0, int mt1, int ec, int T)
{
    __shared__ __align__(16) __hip_bfloat16 As[128 * 32];
    __shared__ __align__(16) __hip_bfloat16 Bs[128 * 32];
    // bijective XCD remap: orig (round-robin xcd = orig&7) -> chunked t
    int orig = blockIdx.x;
    int q = T >> 3, r8 = T & 7;
    int xcd = orig & 7, pos = orig >> 3;
    int t = (xcd < r8 ? xcd * (q + 1) : r8 * (q + 1) + (xcd - r8) * q) + pos;

    int s0 = mt0 * 5, s1 = mt1 * 4;
    if (t < s0) {                       // y0: ncols=5, row-major (A-panel-major)
        gemm_body(As, Bs, A0, B0, bias0, O0, 576, ec, 576, 1920,
                  (t / 5) * 128, (t % 5) * 128, threadIdx.x, 1);
    } else if (t < s0 + s1) {           // y1: ncols=4
        t -= s0;
        gemm_body(As, Bs, A1, B1, (const float*)nullptr, O1, 512, 2 * ec, 512, 1536,
                  (t / 4) * 128, (t % 4) * 128, threadIdx.x, 1);
    } else {                            // y2: ncols=3
        t -= s0 + s1;
        gemm_body(As, Bs, A2, B2, (const float*)nullptr, O2, 384, 2 * ec, 384, 1152,
                  (t / 3) * 128, (t % 3) * 128, threadIdx.x, 1);
    }
}

// ---------------------------------------------------------------------------
// K3 v6: enforced preload + nontemporal streams (unchanged from round 7)
__global__ __launch_bounds__(384) void k_build_mp(
    const float* __restrict__ x, const float* __restrict__ ef, const float* __restrict__ wgn,
    const float* __restrict__ wrad, const int* __restrict__ eidx,
    __hip_bfloat16* __restrict__ A0, __hip_bfloat16* __restrict__ A1,
    __hip_bfloat16* __restrict__ A2, int e0, int E)
{
    __shared__ __align__(16) float swig[512];   // [25][20] transposed, j padded
    int tid = threadIdx.x;
    int le = blockIdx.x;
    long e = e0 + le;
    int src = eidx[e], tgt = eidx[E + e];

    for (int i = tid; i < 500; i += 384) {
        int n = i / 20, j = i - n * 20;
        swig[i] = (j < 19) ? __builtin_nontemporal_load(
                                 &wgn[e * 625 + c_MASKP[j] * 25 + n]) : 0.f;
    }

    int c = tid;  // 0..383 (wave-uniform branch: waves 0-1 src, 2-3 tgt, 4-5 ef)
    float vals[25];
    if (c < 256) {
        const float* base = (c < 128) ? (x + (long)src * 3200 + c)
                                      : (x + (long)tgt * 3200 + (c - 128));
        #pragma unroll
        for (int n = 0; n < 25; ++n) vals[n] = base[n * 128];
    } else {
        const float* base = ef + e * 3200 + (c - 256);
        #pragma unroll
        for (int n = 0; n < 25; ++n)
            vals[n] = __builtin_nontemporal_load(&base[n * 128]);
    }
    float rad[5];
    #pragma unroll
    for (int l = 0; l < 5; ++l)
        rad[l] = __builtin_nontemporal_load(&wrad[(long)le * 1920 + l * 384 + c]);

    // force all 30 loads to be issued and live before consumption (rule #17)
    asm volatile("" ::
        "v"(vals[0]),  "v"(vals[1]),  "v"(vals[2]),  "v"(vals[3]),  "v"(vals[4]),
        "v"(vals[5]),  "v"(vals[6]),  "v"(vals[7]),  "v"(vals[8]),  "v"(vals[9]),
        "v"(vals[10]), "v"(vals[11]), "v"(vals[12]), "v"(vals[13]), "v"(vals[14]),
        "v"(vals[15]), "v"(vals[16]), "v"(vals[17]), "v"(vals[18]), "v"(vals[19]),
        "v"(vals[20]), "v"(vals[21]), "v"(vals[22]), "v"(vals[23]), "v"(vals[24]),
        "v"(rad[0]), "v"(rad[1]), "v"(rad[2]), "v"(rad[3]), "v"(rad[4]));

    #pragma unroll
    for (int n = 0; n < 25; ++n) vals[n] *= rad[c_LFULL[n]];

    __syncthreads();
    const float4* sw = (const float4*)swig;

    float acc[20] = {};
    #pragma unroll
    for (int n = 0; n < 25; ++n) {
        float v = vals[n];
        #pragma unroll
        for (int q = 0; q < 5; ++q) {
            float4 wv = sw[n * 5 + q];
            acc[q * 4 + 0] += wv.x * v;
            acc[q * 4 + 1] += wv.y * v;
            acc[q * 4 + 2] += wv.z * v;
            acc[q * 4 + 3] += wv.w * v;
        }
    }

    #pragma unroll
    for (int j = 0; j < 19; ++j) {
        __hip_bfloat16 hv = __float2bfloat16(acc[j]);
        if (j < 5)       A0[(long)le * 1920 + j * 384 + c] = hv;
        else if (j < 9)  A1[(long)(2 * le)     * 1536 + (j - 5)  * 384 + c] = hv;
        else if (j < 13) A1[(long)(2 * le + 1) * 1536 + (j - 9)  * 384 + c] = hv;
        else if (j < 16) A2[(long)(2 * le)     * 1152 + (j - 13) * 384 + c] = hv;
        else             A2[(long)(2 * le + 1) * 1152 + (j - 16) * 384 + c] = hv;
    }
}

// ---------------------------------------------------------------------------
// K5a v2: recombine + gate + transposed Wigner -> sful as split-bf16 rows.
__global__ __launch_bounds__(256) void k_combine_a(
    const float* __restrict__ wgn, const float* __restrict__ ym0,
    const float* __restrict__ ym1, const float* __restrict__ ym2,
    __hip_bfloat16* __restrict__ sfl, int e0, int CE)
{
    __shared__ __align__(16) float swig[512];   // [25][20] transposed, j padded
    __shared__ float shl[1216];   // 19 x 64
    int tid = threadIdx.x;
    int le = blockIdx.x;
    long e = e0 + le;

    for (int i = tid; i < 500; i += 256) {
        int n = i / 20, j = i - n * 20;
        swig[i] = (j < 19) ? __builtin_nontemporal_load(
                                 &wgn[e * 625 + c_MASKP[j] * 25 + n]) : 0.f;
    }

    const float* y0  = ym0 + (long)le * 576;
    const float* y1a = ym1 + (long)(2 * le) * 512;
    const float* y1b = ym1 + (long)(2 * le + 1) * 512;
    const float* y2a = ym2 + (long)(2 * le) * 384;
    const float* y2b = ym2 + (long)(2 * le + 1) * 384;

    for (int i = tid; i < 1216; i += 256) {
        int j = i >> 6, c = i & 63;
        float raw;
        if (j < 5)        raw = y0[256 + j * 64 + c];
        else if (j < 9)   { int k = (j - 5) * 64 + c;  raw = y1a[k] - y1b[256 + k]; }
        else if (j < 13)  { int k = (j - 9) * 64 + c;  raw = y1b[k] + y1a[256 + k]; }
        else if (j < 16)  { int k = (j - 13) * 64 + c; raw = y2a[k] - y2b[192 + k]; }
        else              { int k = (j - 16) * 64 + c; raw = y2b[k] + y2a[192 + k]; }
        float v;
        if (j == 0) v = raw * sigm_(raw);
        else        v = raw * sigm_(y0[c_GATEP[j] * 64 + c]);
        shl[i] = v;
    }
    __syncthreads();

    for (int i = tid; i < 1600; i += 256) {
        int n = i >> 6, c = i & 63;          // n uniform per wave -> swig broadcast
        const float4* sw = (const float4*)swig + n * 5;
        float acc = 0.f;
        float4 w0 = sw[0], w1 = sw[1], w2 = sw[2], w3 = sw[3], w4 = sw[4];
        acc += w0.x * shl[ 0 * 64 + c];
        acc += w0.y * shl[ 1 * 64 + c];
        acc += w0.z * shl[ 2 * 64 + c];
        acc += w0.w * shl[ 3 * 64 + c];
        acc += w1.x * shl[ 4 * 64 + c];
        acc += w1.y * shl[ 5 * 64 + c];
        acc += w1.z * shl[ 6 * 64 + c];
        acc += w1.w * shl[ 7 * 64 + c];
        acc += w2.x * shl[ 8 * 64 + c];
        acc += w2.y * shl[ 9 * 64 + c];
        acc += w2.z * shl[10 * 64 + c];
        acc += w2.w * shl[11 * 64 + c];
        acc += w3.x * shl[12 * 64 + c];
        acc += w3.y * shl[13 * 64 + c];
        acc += w3.z * shl[14 * 64 + c];
        acc += w3.w * shl[15 * 64 + c];
        acc += w4.x * shl[16 * 64 + c];
        acc += w4.y * shl[17 * 64 + c];
        acc += w4.z * shl[18 * 64 + c];
        __hip_bfloat16 hi = __float2bfloat16(acc);
        __hip_bfloat16 lo = __float2bfloat16(acc - __bfloat162float(hi));
        int l = c_LFULL[n];
        int nb = l * l, cnt = 2 * l + 1, ni = n - nb;
        long row = (long)CE * nb + (long)le * cnt + ni;
        sfl[row * 192 + c]       = hi;
        sfl[row * 192 + 64 + c]  = hi;
        sfl[row * 192 + 128 + c] = lo;
    }
}

// ---------------------------------------------------------------------------
// K5b: merged projection GEMM over all 5 l-segments.
__global__ __launch_bounds__(256) void k_proj_gemm(
    const __hip_bfloat16* __restrict__ sfl,
    const __hip_bfloat16* __restrict__ pwb,
    const float* __restrict__ pb,
    float* __restrict__ out, int ec, int CE)
{
    __shared__ __align__(16) __hip_bfloat16 As[128 * 32];
    __shared__ __align__(16) __hip_bfloat16 Bs[128 * 32];
    int tid = threadIdx.x;
    int ln = tid & 63, w = tid >> 6;
    int wm = w & 1, wn = w >> 1;

    // locate l-segment (monotone scan, no break)
    int bid = blockIdx.x;
    int l = 0, base = 0;
    #pragma unroll
    for (int ll = 0; ll < 5; ++ll) {
        int tiles = (ec * (2 * ll + 1) + 127) >> 7;
        if (bid >= base + tiles) { base += tiles; l = ll + 1; }
    }
    if (l > 4) return;
    int cnt = 2 * l + 1, nb = l * l;
    int realM = ec * cnt;
    int r0 = (bid - base) * 128;

    const __hip_bfloat16* A = sfl + (long)CE * nb * 192;
    const __hip_bfloat16* B = pwb + l * 128 * 192;

    floatx4 acc[4][4] = {};

    int srow = w * 16 + (ln >> 2);
    int scol = (ln & 3) * 8;
    const __hip_bfloat16* Ag = A + (long)(r0 + srow) * 192 + scol;
    const __hip_bfloat16* Bg = B + (long)srow * 192 + scol;
    __hip_bfloat16* AsW = As + (w * 16) * 32;
    __hip_bfloat16* BsW = Bs + (w * 16) * 32;

    int lrow = ln & 15, lk = (ln >> 4) * 8;

    for (int kk = 0; kk < 192; kk += 32) {
        async16(Ag + kk, AsW);
        async16(Ag + (long)64 * 192 + kk, AsW + 64 * 32);
        async16(Bg + kk, BsW);
        async16(Bg + (long)64 * 192 + kk, BsW + 64 * 32);
        __syncthreads();
        bf16x8 af[4], bf[4];
        #pragma unroll
        for (int mi = 0; mi < 4; ++mi)
            af[mi] = *(const bf16x8*)&As[(wm * 64 + mi * 16 + lrow) * 32 + lk];
        #pragma unroll
        for (int ni = 0; ni < 4; ++ni)
            bf[ni] = *(const bf16x8*)&Bs[(wn * 64 + ni * 16 + lrow) * 32 + lk];
        #pragma unroll
        for (int mi = 0; mi < 4; ++mi)
            #pragma unroll
            for (int ni = 0; ni < 4; ++ni)
                acc[mi][ni] = __builtin_amdgcn_mfma_f32_16x16x32_bf16(
                    af[mi], bf[ni], acc[mi][ni], 0, 0, 0);
        __syncthreads();
    }

    int lq = ln >> 4;
    #pragma unroll
    for (int mi = 0; mi < 4; ++mi) {
        #pragma unroll
        for (int r = 0; r < 4; ++r) {
            int row = r0 + wm * 64 + mi * 16 + lq * 4 + r;
            if (row >= realM) continue;
            int e = row / cnt;
            int nn = nb + (row - e * cnt);
            float* op = out + (long)e * 3200 + (long)nn * 128;
            #pragma unroll
            for (int nib = 0; nib < 4; ++nib) {
                int col = wn * 64 + nib * 16 + lrow;
                float bv = (l == 0) ? pb[col] : 0.f;
                op[col] = acc[mi][nib][r] + bv;
            }
        }
    }
}

// ---------------------------------------------------------------------------
extern "C" void kernel_launch(void* const* d_in, const int* in_sizes, int n_in,
                              void* d_out, int out_size, void* d_ws, size_t ws_size,
                              hipStream_t stream)
{
    const float* x    = (const float*)d_in[0];
    const float* ef   = (const float*)d_in[1];
    const float* ed   = (const float*)d_in[2];
    const float* wgn  = (const float*)d_in[3];
    const float* se   = (const float*)d_in[4];
    const float* te   = (const float*)d_in[5];
    const float* w1   = (const float*)d_in[6];
    const float* b1   = (const float*)d_in[7];
    const float* g1   = (const float*)d_in[8];
    const float* bb1  = (const float*)d_in[9];
    const float* w2   = (const float*)d_in[10];
    const float* b2   = (const float*)d_in[11];
    const float* g2   = (const float*)d_in[12];
    const float* bb2  = (const float*)d_in[13];
    const float* w3   = (const float*)d_in[14];
    const float* b3   = (const float*)d_in[15];
    const float* wm0  = (const float*)d_in[16];
    const float* bm0  = (const float*)d_in[17];
    const float* wm1  = (const float*)d_in[18];
    const float* wm2  = (const float*)d_in[19];
    const float* pw   = (const float*)d_in[20];
    const float* pb   = (const float*)d_in[21];
    const int*   an   = (const int*)d_in[22];
    const int*   eidx = (const int*)d_in[23];
    float* out = (float*)d_out;
    char*  ws  = (char*)d_ws;

    const int E = in_sizes[23] / 2;           // 10000

    size_t off = 0;
    __hip_bfloat16* pwb = (__hip_bfloat16*)(ws + off); off += 5L * 128 * 192 * 2;
    __hip_bfloat16* Wb0 = (__hip_bfloat16*)(ws + off); off += 640L  * 1920 * 2;
    __hip_bfloat16* Wb1 = (__hip_bfloat16*)(ws + off); off += 512L  * 1536 * 2;
    __hip_bfloat16* Wb2 = (__hip_bfloat16*)(ws + off); off += 384L  * 1152 * 2;
    __hip_bfloat16* Wb3 = (__hip_bfloat16*)(ws + off); off += 1920L * 128  * 2;
    __hip_bfloat16* W1b = (__hip_bfloat16*)(ws + off); off += 128L  * 1152 * 2;
    __hip_bfloat16* W2b = (__hip_bfloat16*)(ws + off); off += 128L  * 384  * 2;
    size_t fixedBytes = off;

    long usable = (long)ws_size - (long)fixedBytes;
    long ceRaw = usable / 45696;
    long Epad = ((long)E + 127) & ~127L;
    long CE = ceRaw & ~127L;
    if (CE > Epad) CE = Epad;
    if (CE < 128) CE = 128;

    __hip_bfloat16* h2b = (__hip_bfloat16*)(ws + off); off += CE * 128 * 2;
    float* wrad = (float*)(ws + off);                  off += CE * 1920 * 4;
    __hip_bfloat16* A0 = (__hip_bfloat16*)(ws + off);  off += CE * 1920 * 2;
    __hip_bfloat16* A1 = (__hip_bfloat16*)(ws + off);  off += 2 * CE * 1536 * 2;
    __hip_bfloat16* A2 = (__hip_bfloat16*)(ws + off);  off += 2 * CE * 1152 * 2;
    float* y0 = (float*)(ws + off);                    off += CE * 576 * 4;
    float* y1 = (float*)(ws + off);                    off += 2 * CE * 512 * 4;
    float* y2 = (float*)(ws + off);                    off += 2 * CE * 384 * 4;
    __hip_bfloat16* sfl = (__hip_bfloat16*)(ws + off); off += CE * 25 * 192 * 2;
    __hip_bfloat16* xeb = (__hip_bfloat16*)(ws + off); off += CE * 1152 * 2;
    float* h1 = (float*)(ws + off);                    off += CE * 128 * 4;
    __hip_bfloat16* h1s = (__hip_bfloat16*)(ws + off); off += CE * 384 * 2;
    float* h2 = (float*)(ws + off);                    off += CE * 128 * 4;

    k_split_pw<<<160, 256, 0, stream>>>(pw, pwb);
    k_cvt_w<<<(640 * 1920 + 255) / 256, 256, 0, stream>>>(wm0 + 512L * 1920, Wb0, 576, 640, 1920);
    k_cvt_w<<<(512 * 1536 + 255) / 256, 256, 0, stream>>>(wm1, Wb1, 512, 512, 1536);
    k_cvt_w<<<(384 * 1152 + 255) / 256, 256, 0, stream>>>(wm2, Wb2, 384, 384, 1152);
    k_cvt_w<<<(1920 * 128 + 255) / 256, 256, 0, stream>>>(w3, Wb3, 1920, 1920, 128);
    k_cvt_w_split<<<(128 * 384 + 255) / 256, 256, 0, stream>>>(w1, W1b, 128, 384);
    k_cvt_w_split<<<(128 * 128 + 255) / 256, 256, 0, stream>>>(w2, W2b, 128, 128);

    for (int e0 = 0; e0 < E; e0 += (int)CE) {
        int ec = (E - e0 < (int)CE) ? (E - e0) : (int)CE;
        int Mp  = (ec + 127) & ~127;
        int Mp2 = (2 * ec + 127) & ~127;
        int mt0 = Mp / 128, mt1 = Mp2 / 128;

        // --- radial MLP front as MFMA GEMMs ---
        k_build_xedge<<<dim3((ec * 384 + 255) / 256), 256, 0, stream>>>(
            ed, se, te, an, eidx, xeb, e0, ec, E);
        k_mfma_gemm<<<dim3(mt0, 1), 256, 0, stream>>>(
            xeb, W1b, b1, h1, 128, ec, 128, 1152);
        k_ln_silu<<<dim3((ec + 3) / 4), 256, 0, stream>>>(h1, g1, bb1, h1s, ec, 1);
        k_mfma_gemm<<<dim3(mt0, 1), 256, 0, stream>>>(
            h1s, W2b, b2, h2, 128, ec, 128, 384);
        k_ln_silu<<<dim3((ec + 3) / 4), 256, 0, stream>>>(h2, g2, bb2, h2b, ec, 0);

        k_mfma_gemm<<<dim3(mt0, 1920 / 128), 256, 0, stream>>>(
            h2b, Wb3, b3, wrad, 1920, ec, 1920, 128);

        k_build_mp<<<dim3(ec), 384, 0, stream>>>(
            x, ef, wgn, wrad, eidx, A0, A1, A2, e0, E);

        // y0 + y1 + y2 merged, A-panel-major + XCD-chunked
        int T = mt0 * 5 + mt1 * 7;
        k_mfma_gemm3<<<dim3(T), 256, 0, stream>>>(
            A0, Wb0, bm0 + 512, y0, A1, Wb1, y1, A2, Wb2, y2, mt0, mt1, ec, T);

        k_combine_a<<<dim3(ec), 256, 0, stream>>>(wgn, y0, y1, y2, sfl, e0, (int)CE);

        int tilesTot = 0;
        for (int l = 0; l < 5; ++l) tilesTot += (ec * (2 * l + 1) + 127) >> 7;
        k_proj_gemm<<<dim3(tilesTot), 256, 0, stream>>>(
            sfl, pwb, pb, out + (long)e0 * 3200, ec, (int)CE);
    }
}